// Round 5
// baseline (410.161 us; speedup 1.0000x reference)
//
#include <hip/hip_runtime.h>
#include <hip/hip_fp16.h>
#include <math.h>

// SSIM3D on (8,1,32,256,256) f32, separable Gaussian (5,11,11).
// Occupancy-first redesign: fp16 LDS planes (19.4KB -> 8 blocks/CU),
// in-place per-field y-conv (no tmp buffer), packed-fp16 y-conv math,
// f32 x-conv + SSIM. Stage-1 z-conv stays packed f32 (R4-proven).

typedef __attribute__((ext_vector_type(2))) float f32x2;

#define DEPTH   32
#define HEIGHT  256
#define WIDTH   256
#define HW      (HEIGHT*WIDTH)
#define COUNT   16777216.0
#define NACC    64

#define PDW   22            // half2 (dword) slots per row (44 halo cols)
#define PROWS 44            // rows 0..41 = halo, 42..43 scratch
#define PLSZ  (PROWS*PDW)   // 968 dwords per plane

struct Weights { float wz[5]; float wy[11]; };

__device__ __forceinline__ f32x2 fma2(f32x2 a, f32x2 b, f32x2 c) {
  return __builtin_elementwise_fma(a, b, c);
}
__device__ __forceinline__ f32x2 bc2(float v) { f32x2 r; r.x = v; r.y = v; return r; }

__global__ __launch_bounds__(256, 8) void ssim3d_h16(
    const float* __restrict__ img1, const float* __restrict__ img2,
    double* __restrict__ acc, Weights W)
{
  __shared__ __align__(16) __half2 PL[5 * PLSZ];   // 19,360 B
  __shared__ float wred[4];
  const int tid = threadIdx.x;

  // XCD swizzle: one batch n per XCD (16384 blocks, 8 XCDs)
  int bid = blockIdx.x;
  bid = (bid & 7) * 2048 + (bid >> 3);
  const int txi = bid & 7, tyi = (bid >> 3) & 7, z_out = (bid >> 6) & 31, n = bid >> 11;
  const int x0 = txi * 32 - 6;   // even halo origin (44 cols)
  const int y0 = tyi * 32 - 5;   // rows 0..41 used

  // ---- stage 1: z-conv of 5 fields, column-pair packed f32
  const int cp = tid % 22, g = tid / 22;     // cols {2cp,2cp+1}, rows 4g..4g+3
  f32x2 zacc[4][5];
#pragma unroll
  for (int i = 0; i < 4; ++i)
#pragma unroll
    for (int f = 0; f < 5; ++f) zacc[i][f] = bc2(0.f);

  if (g < 11) {
    const size_t nbase = (size_t)n * DEPTH * HW;
    const int gx0 = x0 + 2 * cp;
    int rofs[4]; float mr[4];
#pragma unroll
    for (int i = 0; i < 4; ++i) {
      int gy = y0 + 4 * g + i;
      int gyc = min(max(gy, 0), 255);
      rofs[i] = gyc * WIDTH;
      mr[i] = ((unsigned)gy < 256u) ? 1.f : 0.f;
    }

    if (gx0 >= 0 && gx0 <= 254) {   // interior: aligned dwordx2 loads
#pragma unroll
      for (int kz = 0; kz < 5; ++kz) {
        int z_in = z_out + kz - 2;
        if ((unsigned)z_in >= 32u) continue;   // zero pad in z
        const f32x2 wz2 = bc2(W.wz[kz]);
        const float* p1 = img1 + nbase + (size_t)z_in * HW + gx0;
        const float* p2 = img2 + nbase + (size_t)z_in * HW + gx0;
#pragma unroll
        for (int i = 0; i < 4; ++i) {
          f32x2 A = *(const f32x2*)(p1 + rofs[i]);
          f32x2 B = *(const f32x2*)(p2 + rofs[i]);
          f32x2 t = wz2 * A, u = wz2 * B;
          zacc[i][0] += t;
          zacc[i][1] += u;
          zacc[i][2] = fma2(t, A, zacc[i][2]);
          zacc[i][3] = fma2(u, B, zacc[i][3]);
          zacc[i][4] = fma2(t, B, zacc[i][4]);
        }
      }
#pragma unroll
      for (int i = 0; i < 4; ++i) {
        f32x2 m = bc2(mr[i]);
#pragma unroll
        for (int f = 0; f < 5; ++f) zacc[i][f] *= m;
      }
    } else {   // x-edge tiles: clamped scalar loads + column masks
      const int xo0 = min(max(gx0, 0), 255), xo1 = min(max(gx0 + 1, 0), 255);
      const float mx0 = ((unsigned)gx0 < 256u) ? 1.f : 0.f;
      const float mx1 = ((unsigned)(gx0 + 1) < 256u) ? 1.f : 0.f;
#pragma unroll
      for (int kz = 0; kz < 5; ++kz) {
        int z_in = z_out + kz - 2;
        if ((unsigned)z_in >= 32u) continue;
        const f32x2 wz2 = bc2(W.wz[kz]);
        const float* p1 = img1 + nbase + (size_t)z_in * HW;
        const float* p2 = img2 + nbase + (size_t)z_in * HW;
#pragma unroll
        for (int i = 0; i < 4; ++i) {
          f32x2 A, B;
          A.x = p1[rofs[i] + xo0]; A.y = p1[rofs[i] + xo1];
          B.x = p2[rofs[i] + xo0]; B.y = p2[rofs[i] + xo1];
          f32x2 t = wz2 * A, u = wz2 * B;
          zacc[i][0] += t;
          zacc[i][1] += u;
          zacc[i][2] = fma2(t, A, zacc[i][2]);
          zacc[i][3] = fma2(u, B, zacc[i][3]);
          zacc[i][4] = fma2(t, B, zacc[i][4]);
        }
      }
#pragma unroll
      for (int i = 0; i < 4; ++i) {
        f32x2 m; m.x = mr[i] * mx0; m.y = mr[i] * mx1;
#pragma unroll
        for (int f = 0; f < 5; ++f) zacc[i][f] *= m;
      }
    }

    // ---- stage 2: pack f32x2 -> half2, b32 writes (covers all 44 rows)
#pragma unroll
    for (int i = 0; i < 4; ++i) {
      int row = 4 * g + i;
#pragma unroll
      for (int f = 0; f < 5; ++f)
        PL[f * PLSZ + row * PDW + cp] =
            __float22half2_rn(make_float2(zacc[i][f].x, zacc[i][f].y));
    }
  }
  __syncthreads();   // planes ready

  // fp16 y-weights (broadcast pairs), built once
  __half2 wy2[11];
#pragma unroll
  for (int j = 0; j < 11; ++j) wy2[j] = __float2half2_rn(W.wy[j]);

  // ---- stage 3: per-field in-place y-conv (packed fp16)
  // thread: g2=tid/22 -> rows 3g2..3g2+2 (33>=32), xp=tid%22 -> col pair
  const int g2 = tid / 22, xp = tid % 22;
  const bool act3 = (g2 < 11);
#pragma unroll
  for (int f = 0; f < 5; ++f) {
    __half2 yout[3];
    if (act3) {
      const __half2* pf = PL + f * PLSZ + xp;
      __half2 win[13];
#pragma unroll
      for (int i = 0; i < 13; ++i) win[i] = pf[(3 * g2 + i) * PDW];
#pragma unroll
      for (int r = 0; r < 3; ++r) {
        __half2 s = __float2half2_rn(0.f);
#pragma unroll
        for (int j = 0; j < 11; ++j) s = __hfma2(wy2[j], win[r + j], s);
        yout[r] = s;
      }
    }
    __syncthreads();   // all reads of plane f done
    if (act3) {
#pragma unroll
      for (int r = 0; r < 3; ++r) {
        int y = 3 * g2 + r;
        if (y < 32) PL[f * PLSZ + y * PDW + xp] = yout[r];
      }
    }
    // no sync needed before next field: different plane
  }
  __syncthreads();   // all y-writes visible

  // ---- stage 4: x-conv (f32) + SSIM; thread -> row yy, out cols xq..xq+3
  const int yy = tid >> 3, xq2 = (tid & 7) << 2;   // xq2 in {0,4,...,28}
  float sf[5][4];
#pragma unroll
  for (int f = 0; f < 5; ++f) {
    const uint2* pp = (const uint2*)(PL + f * PLSZ + yy * PDW + (xq2 >> 1));
    uint2 d0 = pp[0], d1 = pp[1], d2 = pp[2], d3 = pp[3];
    unsigned dw[8] = {d0.x, d0.y, d1.x, d1.y, d2.x, d2.y, d3.x, d3.y};
    float w[16];
#pragma unroll
    for (int m = 0; m < 8; ++m) {
      __half2 h = *(__half2*)&dw[m];
      float2 fp = __half22float2(h);
      w[2 * m] = fp.x; w[2 * m + 1] = fp.y;
    }
#pragma unroll
    for (int k = 0; k < 4; ++k) {
      float sv = 0.f;
#pragma unroll
      for (int j = 0; j < 11; ++j) sv = fmaf(W.wy[j], w[k + j], sv);
      sf[f][k] = sv;
    }
  }

  float lsum = 0.f;
  const float C1 = 1e-4f, C2 = 9e-4f;
#pragma unroll
  for (int k = 0; k < 4; ++k) {
    float mu1 = sf[0][k], mu2 = sf[1][k];
    float m11 = mu1 * mu1, m22 = mu2 * mu2, m12 = mu1 * mu2;
    float s1 = sf[2][k] - m11, s2 = sf[3][k] - m22, s12 = sf[4][k] - m12;
    float num = fmaf(2.f, m12, C1) * fmaf(2.f, s12, C2);
    float den = (m11 + m22 + C1) * (s1 + s2 + C2);
#if __has_builtin(__builtin_amdgcn_rcpf)
    lsum = fmaf(num, __builtin_amdgcn_rcpf(den), lsum);
#else
    lsum += num / den;
#endif
  }

  // ---- reduction
#pragma unroll
  for (int off = 32; off > 0; off >>= 1) lsum += __shfl_down(lsum, off, 64);
  if ((tid & 63) == 0) wred[tid >> 6] = lsum;
  __syncthreads();
  if (tid == 0) {
    float bs = wred[0] + wred[1] + wred[2] + wred[3];
    atomicAdd(&acc[blockIdx.x & (NACC - 1)], (double)bs);
  }
}

__global__ void ssim3d_finalize(const double* __restrict__ acc, float* __restrict__ out)
{
  double s = 0.0;
  for (int i = 0; i < NACC; ++i) s += acc[i];
  out[0] = 1.0f - (float)(s / COUNT);
}

static Weights make_weights()
{
  Weights W;
  double gbuf[11]; double s;

  s = 0.0;
  for (int i = 0; i < 5; ++i) {
    double d = i - 2;
    gbuf[i] = exp(-(d * d) / (2.0 * 0.7 * 0.7));
    s += gbuf[i];
  }
  for (int i = 0; i < 5; ++i) W.wz[i] = (float)(gbuf[i] / s);

  s = 0.0;
  for (int i = 0; i < 11; ++i) {
    double d = i - 5;
    gbuf[i] = exp(-(d * d) / (2.0 * 1.5 * 1.5));
    s += gbuf[i];
  }
  for (int i = 0; i < 11; ++i) W.wy[i] = (float)(gbuf[i] / s);

  return W;
}

extern "C" void kernel_launch(void* const* d_in, const int* in_sizes, int n_in,
                              void* d_out, int out_size, void* d_ws, size_t ws_size,
                              hipStream_t stream)
{
  const float* img1 = (const float*)d_in[0];
  const float* img2 = (const float*)d_in[1];
  float* out = (float*)d_out;
  double* acc = (double*)d_ws;

  hipMemsetAsync(d_ws, 0, NACC * sizeof(double), stream);

  Weights W = make_weights();

  const int n_blocks = 8 * DEPTH * 8 * 8;   // 16384
  ssim3d_h16<<<dim3(n_blocks), dim3(256), 0, stream>>>(img1, img2, acc, W);
  ssim3d_finalize<<<1, 1, 0, stream>>>(acc, out);
}

// Round 6
// 131.437 us; speedup vs baseline: 3.1206x; 3.1206x over previous
//
#include <hip/hip_runtime.h>
#include <hip/hip_fp16.h>
#include <math.h>

// SSIM3D on (8,1,32,256,256) f32, separable Gaussian (5,11,11).
// fp16 LDS planes (19.4KB -> 8 blocks/CU by LDS), launch_bounds(256,4) so the
// allocator does NOT spill (R5 lesson: (256,8) forced 32 VGPR + 1.5GB scratch).
// Mask-free edges: even-aligned 44-col halo => column pairs are all-in or
// all-out (zeros, no load); OOB rows zeroed at stage-3 read (uniform branch).

typedef __attribute__((ext_vector_type(2))) float f32x2;

#define DEPTH   32
#define HEIGHT  256
#define WIDTH   256
#define HW      (HEIGHT*WIDTH)
#define COUNT   16777216.0
#define NACC    64

#define PDW   22            // half2 slots per row (44 halo cols)
#define PROWS 44            // rows 0..41 = halo, 42..43 scratch
#define PLSZ  (PROWS*PDW)   // 968 dwords per plane

struct Weights { float wz[5]; float wy[11]; };

__device__ __forceinline__ f32x2 fma2(f32x2 a, f32x2 b, f32x2 c) {
  return __builtin_elementwise_fma(a, b, c);
}
__device__ __forceinline__ f32x2 bc2(float v) { f32x2 r; r.x = v; r.y = v; return r; }

__global__ __launch_bounds__(256, 4) void ssim3d_h16b(
    const float* __restrict__ img1, const float* __restrict__ img2,
    double* __restrict__ acc, Weights W)
{
  __shared__ __align__(16) __half2 PL[5 * PLSZ];   // 19,360 B
  __shared__ float wred[4];
  const int tid = threadIdx.x;

  // XCD swizzle: one batch n per XCD (16384 blocks, 8 XCDs)
  int bid = blockIdx.x;
  bid = (bid & 7) * 2048 + (bid >> 3);
  const int txi = bid & 7, tyi = (bid >> 3) & 7, z_out = (bid >> 6) & 31, n = bid >> 11;
  const int x0 = txi * 32 - 6;   // even halo origin (44 cols)
  const int y0 = tyi * 32 - 5;   // halo rows 0..41 used

  // ---- stage 1: z-conv of 5 fields, column-pair packed f32 (mask-free)
  const int cp = tid % 22, g = tid / 22;   // cols {2cp,2cp+1}, rows 4g..4g+3
  f32x2 zacc[4][5];
#pragma unroll
  for (int i = 0; i < 4; ++i)
#pragma unroll
    for (int f = 0; f < 5; ++f) zacc[i][f] = bc2(0.f);

  if (g < 11) {
    const int gx0 = x0 + 2 * cp;
    if ((unsigned)gx0 <= 254u) {   // pair fully in-bounds (else stays zero)
      const size_t nbase = (size_t)n * DEPTH * HW;
      int rofs[4];
#pragma unroll
      for (int i = 0; i < 4; ++i) {
        int gy = y0 + 4 * g + i;                 // OOB rows: clamped data,
        rofs[i] = min(max(gy, 0), 255) * WIDTH;  // zeroed at stage-3 read
      }
#pragma unroll
      for (int kz = 0; kz < 5; ++kz) {
        int z_in = z_out + kz - 2;
        if ((unsigned)z_in >= 32u) continue;     // zero pad in z (uniform)
        const f32x2 wz2 = bc2(W.wz[kz]);
        const float* p1 = img1 + nbase + (size_t)z_in * HW + gx0;
        const float* p2 = img2 + nbase + (size_t)z_in * HW + gx0;
#pragma unroll
        for (int i = 0; i < 4; ++i) {
          f32x2 A = *(const f32x2*)(p1 + rofs[i]);
          f32x2 B = *(const f32x2*)(p2 + rofs[i]);
          f32x2 t = wz2 * A, u = wz2 * B;
          zacc[i][0] += t;
          zacc[i][1] += u;
          zacc[i][2] = fma2(t, A, zacc[i][2]);
          zacc[i][3] = fma2(u, B, zacc[i][3]);
          zacc[i][4] = fma2(t, B, zacc[i][4]);
        }
      }
    }
    // ---- stage 2: pack f32x2 -> half2, b32 writes (zeros for OOB pairs)
#pragma unroll
    for (int i = 0; i < 4; ++i) {
      int row = 4 * g + i;
#pragma unroll
      for (int f = 0; f < 5; ++f)
        PL[f * PLSZ + row * PDW + cp] =
            __float22half2_rn(make_float2(zacc[i][f].x, zacc[i][f].y));
    }
  }
  __syncthreads();   // planes ready

  // fp16 y-weights (broadcast pairs)
  __half2 wy2[11];
#pragma unroll
  for (int j = 0; j < 11; ++j) wy2[j] = __float2half2_rn(W.wy[j]);

  // ---- stage 3: per-field in-place y-conv (packed fp16)
  const int g2 = tid / 22, xp = tid % 22;   // rows 3g2..3g2+2, col-pair xp
  const bool act3 = (g2 < 11);
  const bool yedge = (tyi == 0) || (tyi == 7);
#pragma unroll
  for (int f = 0; f < 5; ++f) {
    __half2 yout[3];
    if (act3) {
      const __half2* pf = PL + f * PLSZ + xp;
      __half2 win[13];
#pragma unroll
      for (int i = 0; i < 13; ++i) win[i] = pf[(3 * g2 + i) * PDW];
      if (yedge) {   // block-uniform: zero OOB halo rows
#pragma unroll
        for (int i = 0; i < 13; ++i)
          if ((unsigned)(y0 + 3 * g2 + i) >= 256u) win[i] = __float2half2_rn(0.f);
      }
#pragma unroll
      for (int r = 0; r < 3; ++r) {
        __half2 s = __float2half2_rn(0.f);
#pragma unroll
        for (int j = 0; j < 11; ++j) s = __hfma2(wy2[j], win[r + j], s);
        yout[r] = s;
      }
    }
    __syncthreads();   // all reads of plane f done
    if (act3) {
#pragma unroll
      for (int r = 0; r < 3; ++r) {
        int y = 3 * g2 + r;
        if (y < 32) PL[f * PLSZ + y * PDW + xp] = yout[r];
      }
    }
  }
  __syncthreads();   // all y-writes visible

  // ---- stage 4: x-conv (f32) + SSIM; row = tid&31 (2-way-max LDS banks)
  const int yy = tid & 31;
  const int xh = tid >> 5;          // 0..7 -> out cols 4xh..4xh+3
  float sf[5][4];
#pragma unroll
  for (int f = 0; f < 5; ++f) {
    const uint2* pp = (const uint2*)(PL + f * PLSZ + yy * PDW + xh * 2);
    uint2 d0 = pp[0], d1 = pp[1], d2 = pp[2], d3 = pp[3];
    unsigned dw[8] = {d0.x, d0.y, d1.x, d1.y, d2.x, d2.y, d3.x, d3.y};
    float w[16];
#pragma unroll
    for (int m = 0; m < 8; ++m) {
      float2 fp = __half22float2(*(__half2*)&dw[m]);
      w[2 * m] = fp.x; w[2 * m + 1] = fp.y;
    }
#pragma unroll
    for (int k = 0; k < 4; ++k) {
      float sv = 0.f;
#pragma unroll
      for (int j = 0; j < 11; ++j)            // halo col = out_col + 1 + j
        sv = fmaf(W.wy[j], w[k + 1 + j], sv); // (x0=-6 => +1 shift)
      sf[f][k] = sv;
    }
  }

  float lsum = 0.f;
  const float C1 = 1e-4f, C2 = 9e-4f;
#pragma unroll
  for (int k = 0; k < 4; ++k) {
    float mu1 = sf[0][k], mu2 = sf[1][k];
    float m11 = mu1 * mu1, m22 = mu2 * mu2, m12 = mu1 * mu2;
    float s1 = sf[2][k] - m11, s2 = sf[3][k] - m22, s12 = sf[4][k] - m12;
    float num = fmaf(2.f, m12, C1) * fmaf(2.f, s12, C2);
    float den = (m11 + m22 + C1) * (s1 + s2 + C2);
#if __has_builtin(__builtin_amdgcn_rcpf)
    lsum = fmaf(num, __builtin_amdgcn_rcpf(den), lsum);
#else
    lsum += num / den;
#endif
  }

  // ---- reduction
#pragma unroll
  for (int off = 32; off > 0; off >>= 1) lsum += __shfl_down(lsum, off, 64);
  if ((tid & 63) == 0) wred[tid >> 6] = lsum;
  __syncthreads();
  if (tid == 0) {
    float bs = wred[0] + wred[1] + wred[2] + wred[3];
    atomicAdd(&acc[blockIdx.x & (NACC - 1)], (double)bs);
  }
}

__global__ void ssim3d_finalize(const double* __restrict__ acc, float* __restrict__ out)
{
  double s = 0.0;
  for (int i = 0; i < NACC; ++i) s += acc[i];
  out[0] = 1.0f - (float)(s / COUNT);
}

static Weights make_weights()
{
  Weights W;
  double gbuf[11]; double s;

  s = 0.0;
  for (int i = 0; i < 5; ++i) {
    double d = i - 2;
    gbuf[i] = exp(-(d * d) / (2.0 * 0.7 * 0.7));
    s += gbuf[i];
  }
  for (int i = 0; i < 5; ++i) W.wz[i] = (float)(gbuf[i] / s);

  s = 0.0;
  for (int i = 0; i < 11; ++i) {
    double d = i - 5;
    gbuf[i] = exp(-(d * d) / (2.0 * 1.5 * 1.5));
    s += gbuf[i];
  }
  for (int i = 0; i < 11; ++i) W.wy[i] = (float)(gbuf[i] / s);

  return W;
}

extern "C" void kernel_launch(void* const* d_in, const int* in_sizes, int n_in,
                              void* d_out, int out_size, void* d_ws, size_t ws_size,
                              hipStream_t stream)
{
  const float* img1 = (const float*)d_in[0];
  const float* img2 = (const float*)d_in[1];
  float* out = (float*)d_out;
  double* acc = (double*)d_ws;

  hipMemsetAsync(d_ws, 0, NACC * sizeof(double), stream);

  Weights W = make_weights();

  const int n_blocks = 8 * DEPTH * 8 * 8;   // 16384
  ssim3d_h16b<<<dim3(n_blocks), dim3(256), 0, stream>>>(img1, img2, acc, W);
  ssim3d_finalize<<<1, 1, 0, stream>>>(acc, out);
}

// Round 8
// 115.287 us; speedup vs baseline: 3.5577x; 1.1401x over previous
//
#include <hip/hip_runtime.h>

// SSIM3D on (8,1,32,256,256) f32, separable Gaussian (5,11,11).
// fp16-packed pipeline, register-dieted to hit 6 waves/SIMD (gfx950 rule:
// waves/SIMD ~ floor(256/VGPR); R5/R6 evidence). Weights are compile-time
// fp16 literals (SGPR/immediate, zero VGPR cost). LDS 19.4KB fp16 planes.

typedef __attribute__((ext_vector_type(2))) float f32x2;
typedef _Float16 h2 __attribute__((ext_vector_type(2)));

#define DEPTH   32
#define HEIGHT  256
#define WIDTH   256
#define HW      (HEIGHT*WIDTH)
#define COUNT   16777216.0
#define NACC    64

#define PDW   22            // h2 slots per row (44 halo cols)
#define PLSZ  (44*PDW)      // 968 h2 per plane (rows 0..41 halo, 42..43 scratch)

// fp16 bit patterns: wy (sigma=1.5, n=11) and wz (sigma=0.7, n=5), normalized
#define W0h 0x1436u  // 0.00102852
#define W1h 0x1FC8u  // 0.00759876
#define W2h 0x289Cu  // 0.03600077
#define W3h 0x2F00u  // 0.10936070
#define W4h 0x32D1u  // 0.21300540
#define W5h 0x3442u  // 0.26601330

__device__ __forceinline__ h2 h2bits(unsigned u) {
  h2 r; __builtin_memcpy(&r, &u, 4); return r;
}
__device__ __forceinline__ h2 hfma2v(h2 a, h2 b, h2 c) {
  return __builtin_elementwise_fma(a, b, c);
}
__device__ __forceinline__ h2 pkrtz(float x, float y) {
#if __has_builtin(__builtin_amdgcn_cvt_pkrtz)
  auto t = __builtin_amdgcn_cvt_pkrtz(x, y);   // __fp16 ext_vector(2)
  h2 r; __builtin_memcpy(&r, &t, 4); return r;
#else
  h2 r; r.x = (_Float16)x; r.y = (_Float16)y; return r;
#endif
}

__global__ __launch_bounds__(256, 6) void ssim3d_h16c(
    const float* __restrict__ img1, const float* __restrict__ img2,
    double* __restrict__ acc)
{
  __shared__ __align__(16) h2 PL[5 * PLSZ];   // 19,360 B
  __shared__ float wred[4];
  const int tid = threadIdx.x;

  // broadcast fp16 weight constants (folded to SGPR/imm at compile time)
  constexpr unsigned WYB[11] = {
    W0h|(W0h<<16), W1h|(W1h<<16), W2h|(W2h<<16), W3h|(W3h<<16), W4h|(W4h<<16),
    W5h|(W5h<<16),
    W4h|(W4h<<16), W3h|(W3h<<16), W2h|(W2h<<16), W1h|(W1h<<16), W0h|(W0h<<16)};
  constexpr unsigned WZB[5] = {
    0x20ED20EDu, 0x32933293u, 0x388F388Fu, 0x32933293u, 0x20ED20EDu};
  // x-conv weight pairs WP[k][m]: lo16 = wy[2m-k-1], hi16 = wy[2m-k] (OOR -> 0)
  constexpr unsigned WP[4][8] = {
    {0x14360000u, 0x289C1FC8u, 0x32D12F00u, 0x32D13442u, 0x289C2F00u, 0x14361FC8u, 0u, 0u},
    {0u, 0x1FC81436u, 0x2F00289Cu, 0x344232D1u, 0x2F0032D1u, 0x1FC8289Cu, 0x00001436u, 0u},
    {0u, 0x14360000u, 0x289C1FC8u, 0x32D12F00u, 0x32D13442u, 0x289C2F00u, 0x14361FC8u, 0u},
    {0u, 0u, 0x1FC81436u, 0x2F00289Cu, 0x344232D1u, 0x2F0032D1u, 0x1FC8289Cu, 0x00001436u}};

  // ---- block decode + XCD swizzle (one batch n per XCD)
  int bid = blockIdx.x;
  bid = (bid & 7) * 2048 + (bid >> 3);
  const int txi = bid & 7, tyi = (bid >> 3) & 7, z_out = (bid >> 6) & 31, n = bid >> 11;
  const int x0 = txi * 32 - 6;   // even halo origin (44 cols)
  const int y0 = tyi * 32 - 5;   // halo rows 0..41 used

  // ---- stage 1: z-conv of 5 fields, packed fp16 accumulation
  const int cp = tid % 22, g = tid / 22;   // cols {2cp,2cp+1}, rows 4g..4g+3
  h2 zacc[4][5];
#pragma unroll
  for (int i = 0; i < 4; ++i)
#pragma unroll
    for (int f = 0; f < 5; ++f) zacc[i][f] = (h2){(_Float16)0, (_Float16)0};

  if (g < 11) {
    const int gx0 = x0 + 2 * cp;
    if ((unsigned)gx0 <= 254u) {   // pair fully in-bounds (else stays zero)
      const size_t nbase = (size_t)n * DEPTH * HW;
      int rofs[4];
#pragma unroll
      for (int i = 0; i < 4; ++i) {
        int gy = y0 + 4 * g + i;                 // OOB rows: clamped data,
        rofs[i] = min(max(gy, 0), 255) * WIDTH;  // zeroed at stage-3 read
      }
#pragma unroll
      for (int kz = 0; kz < 5; ++kz) {
        int z_in = z_out + kz - 2;
        if ((unsigned)z_in >= 32u) continue;     // zero pad in z (uniform)
        const h2 wzh = h2bits(WZB[kz]);
        const float* p1 = img1 + nbase + (size_t)z_in * HW + gx0;
        const float* p2 = img2 + nbase + (size_t)z_in * HW + gx0;
#pragma unroll
        for (int i = 0; i < 4; ++i) {
          f32x2 A = *(const f32x2*)(p1 + rofs[i]);
          f32x2 B = *(const f32x2*)(p2 + rofs[i]);
          h2 ah = pkrtz(A.x, A.y), bh = pkrtz(B.x, B.y);
          zacc[i][0] = hfma2v(wzh, ah, zacc[i][0]);
          zacc[i][1] = hfma2v(wzh, bh, zacc[i][1]);
          zacc[i][2] = hfma2v(wzh, ah * ah, zacc[i][2]);
          zacc[i][3] = hfma2v(wzh, bh * bh, zacc[i][3]);
          zacc[i][4] = hfma2v(wzh, ah * bh, zacc[i][4]);
        }
      }
    }
    // ---- stage 2: b32 stores (already fp16)
#pragma unroll
    for (int i = 0; i < 4; ++i) {
      int row = 4 * g + i;
#pragma unroll
      for (int f = 0; f < 5; ++f)
        PL[f * PLSZ + row * PDW + cp] = zacc[i][f];
    }
  }
  __syncthreads();   // planes ready

  // ---- stage 3: per-field in-place y-conv (packed fp16)
  const int g2 = tid / 22, xp = tid % 22;   // rows 3g2..3g2+2, col-pair xp
  const bool act3 = (g2 < 11);
  const bool yedge = (tyi == 0) || (tyi == 7);
#pragma unroll
  for (int f = 0; f < 5; ++f) {
    h2 yout[3];
    if (act3) {
      const h2* pf = PL + f * PLSZ + xp;
      h2 win[13];
#pragma unroll
      for (int i = 0; i < 13; ++i) win[i] = pf[(3 * g2 + i) * PDW];
      if (yedge) {   // block-uniform: zero OOB halo rows
#pragma unroll
        for (int i = 0; i < 13; ++i)
          if ((unsigned)(y0 + 3 * g2 + i) >= 256u)
            win[i] = (h2){(_Float16)0, (_Float16)0};
      }
#pragma unroll
      for (int r = 0; r < 3; ++r) {
        h2 s = (h2){(_Float16)0, (_Float16)0};
#pragma unroll
        for (int j = 0; j < 11; ++j) s = hfma2v(h2bits(WYB[j]), win[r + j], s);
        yout[r] = s;
      }
    }
    __syncthreads();   // all reads of plane f done
    if (act3) {
#pragma unroll
      for (int r = 0; r < 3; ++r) {
        int y = 3 * g2 + r;
        if (y < 32) PL[f * PLSZ + y * PDW + xp] = yout[r];
      }
    }
  }
  __syncthreads();   // all y-writes visible

  // ---- stage 4: packed fp16 x-conv + f32 SSIM; row = tid&31, cols 4xh..4xh+3
  const int yy = tid & 31;
  const int xh = tid >> 5;
  float sf[5][4];
#pragma unroll
  for (int f = 0; f < 5; ++f) {
    const h2* pp = PL + f * PLSZ + yy * PDW + xh * 2;
    h2 d[8];
#pragma unroll
    for (int m = 0; m < 8; ++m) d[m] = pp[m];
#pragma unroll
    for (int k = 0; k < 4; ++k) {
      h2 a = (h2){(_Float16)0, (_Float16)0};
#pragma unroll
      for (int m = 0; m < 8; ++m)
        if (WP[k][m]) a = hfma2v(h2bits(WP[k][m]), d[m], a);
      sf[f][k] = (float)a.x + (float)a.y;
    }
  }

  float lsum = 0.f;
  const float C1 = 1e-4f, C2 = 9e-4f;
#pragma unroll
  for (int k = 0; k < 4; ++k) {
    float mu1 = sf[0][k], mu2 = sf[1][k];
    float m11 = mu1 * mu1, m22 = mu2 * mu2, m12 = mu1 * mu2;
    float s1 = sf[2][k] - m11, s2 = sf[3][k] - m22, s12 = sf[4][k] - m12;
    float num = fmaf(2.f, m12, C1) * fmaf(2.f, s12, C2);
    float den = (m11 + m22 + C1) * (s1 + s2 + C2);
#if __has_builtin(__builtin_amdgcn_rcpf)
    lsum = fmaf(num, __builtin_amdgcn_rcpf(den), lsum);
#else
    lsum += num / den;
#endif
  }

  // ---- reduction
#pragma unroll
  for (int off = 32; off > 0; off >>= 1) lsum += __shfl_down(lsum, off, 64);
  if ((tid & 63) == 0) wred[tid >> 6] = lsum;
  __syncthreads();
  if (tid == 0) {
    float bs = wred[0] + wred[1] + wred[2] + wred[3];
    atomicAdd(&acc[blockIdx.x & (NACC - 1)], (double)bs);
  }
}

__global__ void ssim3d_finalize(const double* __restrict__ acc, float* __restrict__ out)
{
  double s = 0.0;
  for (int i = 0; i < NACC; ++i) s += acc[i];
  out[0] = 1.0f - (float)(s / COUNT);
}

extern "C" void kernel_launch(void* const* d_in, const int* in_sizes, int n_in,
                              void* d_out, int out_size, void* d_ws, size_t ws_size,
                              hipStream_t stream)
{
  const float* img1 = (const float*)d_in[0];
  const float* img2 = (const float*)d_in[1];
  float* out = (float*)d_out;
  double* acc = (double*)d_ws;

  (void)hipMemsetAsync(d_ws, 0, NACC * sizeof(double), stream);

  const int n_blocks = 8 * DEPTH * 8 * 8;   // 16384
  ssim3d_h16c<<<dim3(n_blocks), dim3(256), 0, stream>>>(img1, img2, acc);
  ssim3d_finalize<<<1, 1, 0, stream>>>(acc, out);
}